// Round 1
// baseline (10909.880 us; speedup 1.0000x reference)
//
#include <hip/hip_runtime.h>
#include <cstddef>

#define THRESH 1e-6f

__device__ __forceinline__ float thrf(float x) { return x > THRESH ? x : 0.0f; }
__device__ __forceinline__ float sigm(float x) { return 1.0f / (1.0f + expf(-x)); }
__device__ __forceinline__ float hsum4(float4 a) { return a.x + a.y + a.z + a.w; }
__device__ __forceinline__ void pmac(float4& a, float4 u, float4 h) {
    a.x += u.x * h.x; a.y += u.y * h.y; a.z += u.z * h.z; a.w += u.w * h.w;
}
__device__ __forceinline__ void fma4(float4& c, float a, float4 b) {
    c.x += a * b.x; c.y += a * b.y; c.z += a * b.z; c.w += a * b.w;
}

// ---------------------------------------------------------------------------
// K1: fused gather+MLP GEMM (unchanged from previous round — proven).
//   emb[m][n] = thr( sum_k thr(W1[tok[m]][k]+b1[k]) * W2[k][n] + b2[n] )
// ---------------------------------------------------------------------------
__global__ __launch_bounds__(256) void k_embed_gemm(const int* __restrict__ tok,
                                                    const float* __restrict__ W1,
                                                    const float* __restrict__ b1,
                                                    const float* __restrict__ W2,
                                                    const float* __restrict__ b2,
                                                    float* __restrict__ emb) {
    constexpr int BM = 64, BN = 64, BK = 32, K = 512, N = 256;
    __shared__ float As[BK][BM + 1];
    __shared__ float Bs[BK][BN];

    const int tid = threadIdx.x;
    const int bm = blockIdx.x * BM;
    const int bn = blockIdx.y * BN;
    const int tn = (tid & 15) * 4;
    const int tm = (tid >> 4) * 4;

    float acc[4][4] = {};

    for (int k0 = 0; k0 < K; k0 += BK) {
        for (int i = tid; i < BM * BK / 4; i += 256) {
            int c4 = (i & (BK / 4 - 1)) * 4;
            int r  = i / (BK / 4);
            int tv = tok[bm + r];
            float4 v  = *(const float4*)(W1 + (size_t)tv * K + k0 + c4);
            float4 bb = *(const float4*)(b1 + k0 + c4);
            As[c4 + 0][r] = thrf(v.x + bb.x);
            As[c4 + 1][r] = thrf(v.y + bb.y);
            As[c4 + 2][r] = thrf(v.z + bb.z);
            As[c4 + 3][r] = thrf(v.w + bb.w);
        }
        for (int i = tid; i < BK * BN / 4; i += 256) {
            int n4 = (i & 15) * 4;
            int kk = i >> 4;
            *(float4*)&Bs[kk][n4] = *(const float4*)(W2 + (size_t)(k0 + kk) * N + bn + n4);
        }
        __syncthreads();

        for (int k = 0; k < BK; ++k) {
            float a0 = As[k][tm + 0], a1 = As[k][tm + 1];
            float a2 = As[k][tm + 2], a3 = As[k][tm + 3];
            float b0 = Bs[k][tn + 0], b1v = Bs[k][tn + 1];
            float b2v = Bs[k][tn + 2], b3v = Bs[k][tn + 3];
            acc[0][0] += a0 * b0;  acc[0][1] += a0 * b1v;
            acc[0][2] += a0 * b2v; acc[0][3] += a0 * b3v;
            acc[1][0] += a1 * b0;  acc[1][1] += a1 * b1v;
            acc[1][2] += a1 * b2v; acc[1][3] += a1 * b3v;
            acc[2][0] += a2 * b0;  acc[2][1] += a2 * b1v;
            acc[2][2] += a2 * b2v; acc[2][3] += a2 * b3v;
            acc[3][0] += a3 * b0;  acc[3][1] += a3 * b1v;
            acc[3][2] += a3 * b2v; acc[3][3] += a3 * b3v;
        }
        __syncthreads();
    }

    const float4 bv = *(const float4*)(b2 + bn + tn);
    for (int i = 0; i < 4; ++i) {
        int m = bm + tm + i;
        float4 o;
        o.x = thrf(acc[i][0] + bv.x);
        o.y = thrf(acc[i][1] + bv.y);
        o.z = thrf(acc[i][2] + bv.z);
        o.w = thrf(acc[i][3] + bv.w);
        *(float4*)(emb + (size_t)m * N + bn + tn) = o;
    }
}

// ---------------------------------------------------------------------------
// K2 (new): x_proj = emb @ W_ih^T + b_ih.
//   M=4096 (s*32+b), K=256, J=1536.  128x64 tile, BK=32, 256 thr, 8x4 micro.
//   Bias b_ih folded into the epilogue so the scan needs no b_ih at all.
// ---------------------------------------------------------------------------
__global__ __launch_bounds__(256) void k_xproj(const float* __restrict__ emb,   // (4096,256)
                                               const float* __restrict__ W_ih,  // (1536,256)
                                               const float* __restrict__ b_ih,  // (1536)
                                               float* __restrict__ xp) {        // (4096,1536)
    constexpr int BM = 128, BJ = 64, BK = 32, K = 256, J = 1536;
    __shared__ __align__(16) float As[BK][BM + 4];
    __shared__ __align__(16) float Bs[BK][BJ + 4];
    const int tid = threadIdx.x;
    const int bm = blockIdx.x * BM;
    const int bj = blockIdx.y * BJ;
    const int tj = (tid & 15) * 4;    // 4 j per thread
    const int tm = (tid >> 4) * 8;    // 8 m per thread

    float4 acc[8];
#pragma unroll
    for (int i = 0; i < 8; ++i) acc[i] = make_float4(0.f, 0.f, 0.f, 0.f);

    for (int k0 = 0; k0 < K; k0 += BK) {
#pragma unroll
        for (int p = 0; p < 4; ++p) {          // A: 128 rows x 8 float4
            int i = tid + p * 256;
            int c4 = (i & 7) * 4, r = i >> 3;
            float4 v = *(const float4*)(emb + (size_t)(bm + r) * K + k0 + c4);
            As[c4 + 0][r] = v.x; As[c4 + 1][r] = v.y;
            As[c4 + 2][r] = v.z; As[c4 + 3][r] = v.w;
        }
#pragma unroll
        for (int p = 0; p < 2; ++p) {          // B: 64 rows x 8 float4 (k-major -> transposed)
            int i = tid + p * 256;
            int c4 = (i & 7) * 4, r = i >> 3;
            float4 v = *(const float4*)(W_ih + (size_t)(bj + r) * K + k0 + c4);
            Bs[c4 + 0][r] = v.x; Bs[c4 + 1][r] = v.y;
            Bs[c4 + 2][r] = v.z; Bs[c4 + 3][r] = v.w;
        }
        __syncthreads();

#pragma unroll 8
        for (int k = 0; k < BK; ++k) {
            float4 b4 = *(const float4*)&Bs[k][tj];
            float4 a0 = *(const float4*)&As[k][tm];
            float4 a1 = *(const float4*)&As[k][tm + 4];
            fma4(acc[0], a0.x, b4); fma4(acc[1], a0.y, b4);
            fma4(acc[2], a0.z, b4); fma4(acc[3], a0.w, b4);
            fma4(acc[4], a1.x, b4); fma4(acc[5], a1.y, b4);
            fma4(acc[6], a1.z, b4); fma4(acc[7], a1.w, b4);
        }
        __syncthreads();
    }

    const float4 bb = *(const float4*)(b_ih + bj + tj);
#pragma unroll
    for (int i = 0; i < 8; ++i) {
        float4 o = make_float4(acc[i].x + bb.x, acc[i].y + bb.y,
                               acc[i].z + bb.z, acc[i].w + bb.w);
        *(float4*)(xp + (size_t)(bm + tm + i) * J + bj + tj) = o;
    }
}

// ---------------------------------------------------------------------------
// K3 (new): barrier-free GRU scan.  The recurrence is independent per batch:
// 32 blocks x 1024 threads, block b owns batch b for all 128 steps.
//   - h lives entirely in LDS (double-buffered 2x512 f32); no global h, no
//     flags, no fences, no agent atomics, ONE __syncthreads per step.
//   - thread (j = tid>>1, half = tid&1) computes k-half [half*256,+256) of
//     rows {j, 512+j, 1024+j} of W_hh @ h; halves merged via __shfl_xor(1).
//   - W_hh (3 MB) streams from L2 each step; 32 blocks -> ~4/XCD so it stays
//     L2-resident.  FMA floor: 1536*512 MACs / 256 FLOP/cyc = 6144 cy/step.
//   - x_proj row (b_ih pre-folded) prefetched one step ahead (indep of h).
// ---------------------------------------------------------------------------
__global__ __launch_bounds__(1024) void k_scan(const float* __restrict__ xp,    // (4096,1536)
                                               const float* __restrict__ W_hh,  // (1536,512)
                                               const float* __restrict__ b_hh,  // (1536)
                                               float* __restrict__ h_out) {     // (32,512)
    __shared__ __align__(16) float hl[2][512];
    const int tid  = threadIdx.x;
    const int b    = blockIdx.x;
    const int j    = tid >> 1;
    const int half = tid & 1;
    const int k0   = half * 256;

    const float* w0 = W_hh + (size_t)(j)        * 512 + k0;   // r-gate row
    const float* w1 = W_hh + (size_t)(512 + j)  * 512 + k0;   // z-gate row
    const float* w2 = W_hh + (size_t)(1024 + j) * 512 + k0;   // n-gate row

    if (tid < 512) hl[0][tid] = 0.0f;   // h(0) = 0

    // even-lane persistent state: own h[j], hh-biases, current x row
    float hprev = 0.f, bh0 = 0.f, bh1 = 0.f, bh2 = 0.f;
    float xr = 0.f, xz = 0.f, xn = 0.f;
    if (!half) {
        bh0 = b_hh[j]; bh1 = b_hh[512 + j]; bh2 = b_hh[1024 + j];
        const float* x0 = xp + (size_t)b * 1536 + j;          // row (t=0)*32+b
        xr = x0[0]; xz = x0[512]; xn = x0[1024];
    }
    __syncthreads();

    for (int t = 0; t < 128; ++t) {
        const float* hc = hl[t & 1];

        // prefetch x(t+1): independent of h, hides under the dot phase
        float nxr = 0.f, nxz = 0.f, nxn = 0.f;
        if (!half && t < 127) {
            const float* x1 = xp + (size_t)((t + 1) * 32 + b) * 1536 + j;
            nxr = x1[0]; nxz = x1[512]; nxn = x1[1024];
        }

        // dot phase: 3 gates x 256 k per thread; 12 indep fp32 chains
        float4 a0 = make_float4(0.f, 0.f, 0.f, 0.f), a1 = a0, a2 = a0;
#pragma unroll 4
        for (int i = 0; i < 64; ++i) {
            float4 h4 = *(const float4*)(hc + k0 + i * 4);    // LDS broadcast
            float4 u0 = *(const float4*)(w0 + i * 4);
            float4 u1 = *(const float4*)(w1 + i * 4);
            float4 u2 = *(const float4*)(w2 + i * 4);
            pmac(a0, u0, h4); pmac(a1, u1, h4); pmac(a2, u2, h4);
        }
        float s0 = hsum4(a0), s1 = hsum4(a1), s2 = hsum4(a2);
        s0 += __shfl_xor(s0, 1);   // merge k-halves (lanes 2j <-> 2j+1)
        s1 += __shfl_xor(s1, 1);
        s2 += __shfl_xor(s2, 1);

        if (!half) {
            float r  = sigm(xr + s0 + bh0);
            float z  = sigm(xz + s1 + bh1);
            float n  = tanhf(xn + r * (s2 + bh2));
            float hn = (1.0f - z) * n + z * hprev;
            hprev = hn;
            hl[(t & 1) ^ 1][j] = hn;            // write OTHER buffer: race-free
            if (t == 127) h_out[(size_t)b * 512 + j] = hn;
            xr = nxr; xz = nxz; xn = nxn;
        }
        __syncthreads();   // the single per-step barrier (block-local, ~cheap)
    }
}

// ---------------------------------------------------------------------------
// K4: head (unchanged).  out[b][o] = sum_k h[b][k] * W3[k][o] + b3[o]
// ---------------------------------------------------------------------------
__global__ __launch_bounds__(256) void k_head(const float* __restrict__ h,
                                              const float* __restrict__ W3,
                                              const float* __restrict__ b3,
                                              float* __restrict__ out) {
    const int b = blockIdx.x;
    const int o = threadIdx.x;
    const float* hrow = h + (size_t)b * 512;
    float acc = b3[o];
#pragma unroll 8
    for (int k = 0; k < 512; ++k)
        acc += hrow[k] * W3[(size_t)k * 256 + o];
    out[(size_t)b * 256 + o] = acc;
}

// ---------------------------------------------------------------------------
extern "C" void kernel_launch(void* const* d_in, const int* in_sizes, int n_in,
                              void* d_out, int out_size, void* d_ws, size_t ws_size,
                              hipStream_t stream) {
    // setup_inputs() dict order:
    //   0:input 1:W1 2:b1 3:W2 4:b2 5:W_ih 6:W_hh 7:b_ih 8:b_hh 9:W3 10:b3
    const int*   tok  = (const int*)d_in[0];
    const float* W1   = (const float*)d_in[1];
    const float* b1   = (const float*)d_in[2];
    const float* W2   = (const float*)d_in[3];
    const float* b2   = (const float*)d_in[4];
    const float* W_ih = (const float*)d_in[5];
    const float* W_hh = (const float*)d_in[6];
    const float* b_ih = (const float*)d_in[7];
    const float* b_hh = (const float*)d_in[8];
    const float* W3   = (const float*)d_in[9];
    const float* b3   = (const float*)d_in[10];
    float* out = (float*)d_out;
    (void)ws_size;

    // workspace (floats), all regions fully written before read (no memset):
    //   emb  : 4096*256  = 1,048,576 f  (4 MB)
    //   xp   : 4096*1536 = 6,291,456 f  (25.2 MB)
    //   hfin : 32*512    = 16,384 f
    // total ~29.4 MB
    float* ws   = (float*)d_ws;
    float* emb  = ws;
    float* xp   = ws + 1048576;
    float* hfin = ws + 7340032;

    {   // fused embedding MLP (gather+thr folded into A staging)
        dim3 g(4096 / 64, 256 / 64);
        k_embed_gemm<<<g, 256, 0, stream>>>(tok, W1, b1, W2, b2, emb);
    }
    {   // input projections for all timesteps (b_ih folded in)
        dim3 g(4096 / 128, 1536 / 64);
        k_xproj<<<g, 256, 0, stream>>>(emb, W_ih, b_ih, xp);
    }
    // barrier-free batch-parallel GRU scan (h entirely in LDS)
    k_scan<<<32, 1024, 0, stream>>>(xp, W_hh, b_hh, hfin);

    // head on final hidden state
    k_head<<<32, 256, 0, stream>>>(hfin, W3, b3, out);
}

// Round 2
// 3135.956 us; speedup vs baseline: 3.4790x; 3.4790x over previous
//
#include <hip/hip_runtime.h>
#include <cstddef>

#define THRESH 1e-6f

__device__ __forceinline__ float thrf(float x) { return x > THRESH ? x : 0.0f; }
__device__ __forceinline__ float sigm(float x) { return 1.0f / (1.0f + expf(-x)); }
__device__ __forceinline__ void fma4(float4& c, float a, float4 b) {
    c.x += a * b.x; c.y += a * b.y; c.z += a * b.z; c.w += a * b.w;
}

// ---------------------------------------------------------------------------
// K1: fused gather+MLP GEMM (unchanged — proven).
//   emb[m][n] = thr( sum_k thr(W1[tok[m]][k]+b1[k]) * W2[k][n] + b2[n] )
// ---------------------------------------------------------------------------
__global__ __launch_bounds__(256) void k_embed_gemm(const int* __restrict__ tok,
                                                    const float* __restrict__ W1,
                                                    const float* __restrict__ b1,
                                                    const float* __restrict__ W2,
                                                    const float* __restrict__ b2,
                                                    float* __restrict__ emb) {
    constexpr int BM = 64, BN = 64, BK = 32, K = 512, N = 256;
    __shared__ float As[BK][BM + 1];
    __shared__ float Bs[BK][BN];

    const int tid = threadIdx.x;
    const int bm = blockIdx.x * BM;
    const int bn = blockIdx.y * BN;
    const int tn = (tid & 15) * 4;
    const int tm = (tid >> 4) * 4;

    float acc[4][4] = {};

    for (int k0 = 0; k0 < K; k0 += BK) {
        for (int i = tid; i < BM * BK / 4; i += 256) {
            int c4 = (i & (BK / 4 - 1)) * 4;
            int r  = i / (BK / 4);
            int tv = tok[bm + r];
            float4 v  = *(const float4*)(W1 + (size_t)tv * K + k0 + c4);
            float4 bb = *(const float4*)(b1 + k0 + c4);
            As[c4 + 0][r] = thrf(v.x + bb.x);
            As[c4 + 1][r] = thrf(v.y + bb.y);
            As[c4 + 2][r] = thrf(v.z + bb.z);
            As[c4 + 3][r] = thrf(v.w + bb.w);
        }
        for (int i = tid; i < BK * BN / 4; i += 256) {
            int n4 = (i & 15) * 4;
            int kk = i >> 4;
            *(float4*)&Bs[kk][n4] = *(const float4*)(W2 + (size_t)(k0 + kk) * N + bn + n4);
        }
        __syncthreads();

        for (int k = 0; k < BK; ++k) {
            float a0 = As[k][tm + 0], a1 = As[k][tm + 1];
            float a2 = As[k][tm + 2], a3 = As[k][tm + 3];
            float b0 = Bs[k][tn + 0], b1v = Bs[k][tn + 1];
            float b2v = Bs[k][tn + 2], b3v = Bs[k][tn + 3];
            acc[0][0] += a0 * b0;  acc[0][1] += a0 * b1v;
            acc[0][2] += a0 * b2v; acc[0][3] += a0 * b3v;
            acc[1][0] += a1 * b0;  acc[1][1] += a1 * b1v;
            acc[1][2] += a1 * b2v; acc[1][3] += a1 * b3v;
            acc[2][0] += a2 * b0;  acc[2][1] += a2 * b1v;
            acc[2][2] += a2 * b2v; acc[2][3] += a2 * b3v;
            acc[3][0] += a3 * b0;  acc[3][1] += a3 * b1v;
            acc[3][2] += a3 * b2v; acc[3][3] += a3 * b3v;
        }
        __syncthreads();
    }

    const float4 bv = *(const float4*)(b2 + bn + tn);
    for (int i = 0; i < 4; ++i) {
        int m = bm + tm + i;
        float4 o;
        o.x = thrf(acc[i][0] + bv.x);
        o.y = thrf(acc[i][1] + bv.y);
        o.z = thrf(acc[i][2] + bv.z);
        o.w = thrf(acc[i][3] + bv.w);
        *(float4*)(emb + (size_t)m * N + bn + tn) = o;
    }
}

// ---------------------------------------------------------------------------
// K2: x_proj = emb @ W_ih^T + b_ih  (unchanged — worked in R1).
// ---------------------------------------------------------------------------
__global__ __launch_bounds__(256) void k_xproj(const float* __restrict__ emb,   // (4096,256)
                                               const float* __restrict__ W_ih,  // (1536,256)
                                               const float* __restrict__ b_ih,  // (1536)
                                               float* __restrict__ xp) {        // (4096,1536)
    constexpr int BM = 128, BJ = 64, BK = 32, K = 256, J = 1536;
    __shared__ __align__(16) float As[BK][BM + 4];
    __shared__ __align__(16) float Bs[BK][BJ + 4];
    const int tid = threadIdx.x;
    const int bm = blockIdx.x * BM;
    const int bj = blockIdx.y * BJ;
    const int tj = (tid & 15) * 4;
    const int tm = (tid >> 4) * 8;

    float4 acc[8];
#pragma unroll
    for (int i = 0; i < 8; ++i) acc[i] = make_float4(0.f, 0.f, 0.f, 0.f);

    for (int k0 = 0; k0 < K; k0 += BK) {
#pragma unroll
        for (int p = 0; p < 4; ++p) {
            int i = tid + p * 256;
            int c4 = (i & 7) * 4, r = i >> 3;
            float4 v = *(const float4*)(emb + (size_t)(bm + r) * K + k0 + c4);
            As[c4 + 0][r] = v.x; As[c4 + 1][r] = v.y;
            As[c4 + 2][r] = v.z; As[c4 + 3][r] = v.w;
        }
#pragma unroll
        for (int p = 0; p < 2; ++p) {
            int i = tid + p * 256;
            int c4 = (i & 7) * 4, r = i >> 3;
            float4 v = *(const float4*)(W_ih + (size_t)(bj + r) * K + k0 + c4);
            Bs[c4 + 0][r] = v.x; Bs[c4 + 1][r] = v.y;
            Bs[c4 + 2][r] = v.z; Bs[c4 + 3][r] = v.w;
        }
        __syncthreads();

#pragma unroll 8
        for (int k = 0; k < BK; ++k) {
            float4 b4 = *(const float4*)&Bs[k][tj];
            float4 a0 = *(const float4*)&As[k][tm];
            float4 a1 = *(const float4*)&As[k][tm + 4];
            fma4(acc[0], a0.x, b4); fma4(acc[1], a0.y, b4);
            fma4(acc[2], a0.z, b4); fma4(acc[3], a0.w, b4);
            fma4(acc[4], a1.x, b4); fma4(acc[5], a1.y, b4);
            fma4(acc[6], a1.z, b4); fma4(acc[7], a1.w, b4);
        }
        __syncthreads();
    }

    const float4 bb = *(const float4*)(b_ih + bj + tj);
#pragma unroll
    for (int i = 0; i < 8; ++i) {
        float4 o = make_float4(acc[i].x + bb.x, acc[i].y + bb.y,
                               acc[i].z + bb.z, acc[i].w + bb.w);
        *(float4*)(xp + (size_t)(bm + tm + i) * J + bj + tj) = o;
    }
}

// ---------------------------------------------------------------------------
// K3 (new): transpose W_hh (1536,512) -> WT (512,1536) so the scan's
// per-step weight reads are lane-contiguous.  Classic 32x32 LDS tile.
// ---------------------------------------------------------------------------
__global__ __launch_bounds__(256) void k_transpose(const float* __restrict__ src,  // (1536,512)
                                                   float* __restrict__ dst) {      // (512,1536)
    __shared__ float tile[32][33];
    const int bx = blockIdx.x * 32;   // k (col of src)
    const int by = blockIdx.y * 32;   // j (row of src)
    const int tx = threadIdx.x & 31, ty = threadIdx.x >> 5;   // ty: 0..7
#pragma unroll
    for (int i = 0; i < 32; i += 8)
        tile[ty + i][tx] = src[(size_t)(by + ty + i) * 512 + bx + tx];
    __syncthreads();
#pragma unroll
    for (int i = 0; i < 32; i += 8)
        dst[(size_t)(bx + ty + i) * 1536 + by + tx] = tile[tx][ty + i];
}

// ---------------------------------------------------------------------------
// K4 (rewritten): barrier-free batch-split GRU scan with COALESCED weights.
// 32 blocks x 768 threads; block b owns batch b for all 128 steps.
//   - WT[k][j]: thread q owns j4=4q (q in [0,384)), k-half kh = tid>=384.
//     Per k: WT row slice [j4..j4+4) = contiguous float4; a wave's 64 lanes
//     read 1KB contiguous -> fully coalesced (R1's fatal flaw fixed).
//   - h[k] broadcast from LDS (free), 12 indep FMA chains.
//   - k-halves + gate combine via one LDS exchange (pre[2][1536]).
//   - x_proj row prefetched one step ahead into regs (hidden under dot).
//   - FMA floor 6144 cy/step; per-XCD L2 12MB/step ~ 2.8us -> ~3.5us/step.
// ---------------------------------------------------------------------------
__global__ __launch_bounds__(768) void k_scan(const float* __restrict__ xp,    // (4096,1536)
                                              const float* __restrict__ WT,    // (512,1536)
                                              const float* __restrict__ b_hh,  // (1536)
                                              float* __restrict__ h_out) {     // (32,512)
    __shared__ __align__(16) float hl[2][512];
    __shared__ __align__(16) float pre[2][1536];
    const int tid = threadIdx.x;
    const int b   = blockIdx.x;
    const int kh  = tid >= 384;          // wave-uniform (waves 0-5 vs 6-11)
    const int q   = kh ? tid - 384 : tid;
    const int j4  = q * 4;
    const int kb  = kh * 256;
    const float* wcol = WT + (size_t)kb * 1536 + j4;

    if (tid < 512) hl[0][tid] = 0.0f;    // h(0) = 0

    // persistent finalize-thread state (tid < 128): biases + current x row
    float4 bhr = make_float4(0,0,0,0), bhz = bhr, bhn = bhr;
    float4 xr = bhr, xz = bhr, xn = bhr;
    if (tid < 128) {
        const int jf = tid * 4;
        bhr = *(const float4*)(b_hh + jf);
        bhz = *(const float4*)(b_hh + 512 + jf);
        bhn = *(const float4*)(b_hh + 1024 + jf);
        const float* x0 = xp + (size_t)b * 1536;        // row t=0 is (0*32+b)
        xr = *(const float4*)(x0 + jf);
        xz = *(const float4*)(x0 + 512 + jf);
        xn = *(const float4*)(x0 + 1024 + jf);
    }
    __syncthreads();

    for (int t = 0; t < 128; ++t) {
        const int cur = t & 1, nxt = cur ^ 1;

        // prefetch x(t+1): independent of h, latency hidden by the dot loop
        float4 nxr = make_float4(0,0,0,0), nxz = nxr, nxn = nxr;
        if (tid < 128 && t < 127) {
            const float* x1 = xp + (size_t)((t + 1) * 32 + b) * 1536;
            const int jf = tid * 4;
            nxr = *(const float4*)(x1 + jf);
            nxz = *(const float4*)(x1 + 512 + jf);
            nxn = *(const float4*)(x1 + 1024 + jf);
        }

        // ---- dot: out[j4..j4+3] partial over k in [kb, kb+256) ----
        const float* hk = &hl[cur][kb];
        float4 accA = make_float4(0,0,0,0), accB = accA;
#pragma unroll 4
        for (int i = 0; i < 64; ++i) {
            float4 h4 = *(const float4*)(hk + i * 4);                  // LDS broadcast
            const float* wr = wcol + (size_t)(i * 4) * 1536;
            float4 w0 = *(const float4*)(wr);
            float4 w1 = *(const float4*)(wr + 1536);
            float4 w2 = *(const float4*)(wr + 3072);
            float4 w3 = *(const float4*)(wr + 4608);
            fma4(accA, h4.x, w0); fma4(accB, h4.y, w1);
            fma4(accA, h4.z, w2); fma4(accB, h4.w, w3);
        }
        float4 acc = make_float4(accA.x + accB.x, accA.y + accB.y,
                                 accA.z + accB.z, accA.w + accB.w);
        *(float4*)&pre[kh][j4] = acc;
        __syncthreads();

        // ---- finalize gates: 128 threads, 4 consecutive j each ----
        if (tid < 128) {
            const int jf = tid * 4;
            float4 p0a = *(const float4*)&pre[0][jf];
            float4 p0b = *(const float4*)&pre[1][jf];
            float4 p1a = *(const float4*)&pre[0][512 + jf];
            float4 p1b = *(const float4*)&pre[1][512 + jf];
            float4 p2a = *(const float4*)&pre[0][1024 + jf];
            float4 p2b = *(const float4*)&pre[1][1024 + jf];
            float4 hp = *(const float4*)&hl[cur][jf];
            float hn4[4];
            const float* prx[4] = {&xr.x, &xz.x, &xn.x};
#pragma unroll
            for (int c = 0; c < 4; ++c) {
                float sr = (&p0a.x)[c] + (&p0b.x)[c] + (&bhr.x)[c];
                float sz = (&p1a.x)[c] + (&p1b.x)[c] + (&bhz.x)[c];
                float sn = (&p2a.x)[c] + (&p2b.x)[c] + (&bhn.x)[c];
                float r  = sigm((&xr.x)[c] + sr);
                float z  = sigm((&xz.x)[c] + sz);
                float n  = tanhf((&xn.x)[c] + r * sn);
                hn4[c] = (1.0f - z) * n + z * (&hp.x)[c];
            }
            (void)prx;
            float4 hw = make_float4(hn4[0], hn4[1], hn4[2], hn4[3]);
            *(float4*)&hl[nxt][jf] = hw;
            if (t == 127) *(float4*)(h_out + (size_t)b * 512 + jf) = hw;
            xr = nxr; xz = nxz; xn = nxn;
        }
        __syncthreads();
    }
}

// ---------------------------------------------------------------------------
// K5: head (unchanged).
// ---------------------------------------------------------------------------
__global__ __launch_bounds__(256) void k_head(const float* __restrict__ h,
                                              const float* __restrict__ W3,
                                              const float* __restrict__ b3,
                                              float* __restrict__ out) {
    const int b = blockIdx.x;
    const int o = threadIdx.x;
    const float* hrow = h + (size_t)b * 512;
    float acc = b3[o];
#pragma unroll 8
    for (int k = 0; k < 512; ++k)
        acc += hrow[k] * W3[(size_t)k * 256 + o];
    out[(size_t)b * 256 + o] = acc;
}

// ---------------------------------------------------------------------------
extern "C" void kernel_launch(void* const* d_in, const int* in_sizes, int n_in,
                              void* d_out, int out_size, void* d_ws, size_t ws_size,
                              hipStream_t stream) {
    // 0:input 1:W1 2:b1 3:W2 4:b2 5:W_ih 6:W_hh 7:b_ih 8:b_hh 9:W3 10:b3
    const int*   tok  = (const int*)d_in[0];
    const float* W1   = (const float*)d_in[1];
    const float* b1   = (const float*)d_in[2];
    const float* W2   = (const float*)d_in[3];
    const float* b2   = (const float*)d_in[4];
    const float* W_ih = (const float*)d_in[5];
    const float* W_hh = (const float*)d_in[6];
    const float* b_ih = (const float*)d_in[7];
    const float* b_hh = (const float*)d_in[8];
    const float* W3   = (const float*)d_in[9];
    const float* b3   = (const float*)d_in[10];
    float* out = (float*)d_out;
    (void)ws_size;

    // workspace (floats), every region fully written before read:
    //   emb  : 4096*256  = 1,048,576
    //   xp   : 4096*1536 = 6,291,456
    //   WT   : 512*1536  =   786,432
    //   hfin : 32*512    =    16,384      total ~32.6 MB
    float* ws   = (float*)d_ws;
    float* emb  = ws;
    float* xp   = ws + 1048576;
    float* wt   = ws + 7340032;
    float* hfin = ws + 8126464;

    {   // one-time W_hh transpose (k-major for coalesced scan reads)
        dim3 g(512 / 32, 1536 / 32);
        k_transpose<<<g, 256, 0, stream>>>(W_hh, wt);
    }
    {   // fused embedding MLP
        dim3 g(4096 / 64, 256 / 64);
        k_embed_gemm<<<g, 256, 0, stream>>>(tok, W1, b1, W2, b2, emb);
    }
    {   // input projections for all timesteps (b_ih folded in)
        dim3 g(4096 / 128, 1536 / 64);
        k_xproj<<<g, 256, 0, stream>>>(emb, W_ih, b_ih, xp);
    }
    // barrier-free batch-parallel GRU scan (coalesced WT, h in LDS)
    k_scan<<<32, 768, 0, stream>>>(xp, wt, b_hh, hfin);

    // head on final hidden state
    k_head<<<32, 256, 0, stream>>>(hfin, W3, b3, out);
}

// Round 3
// 1159.236 us; speedup vs baseline: 9.4113x; 2.7052x over previous
//
#include <hip/hip_runtime.h>
#include <cstddef>

#define THRESH 1e-6f
#define SPIN_LIMIT (1 << 20)

__device__ __forceinline__ float thrf(float x) { return x > THRESH ? x : 0.0f; }
__device__ __forceinline__ float sigm(float x) { return 1.0f / (1.0f + expf(-x)); }
__device__ __forceinline__ void fma4(float4& c, float a, float4 b) {
    c.x += a * b.x; c.y += a * b.y; c.z += a * b.z; c.w += a * b.w;
}
__device__ __forceinline__ void macc4(float4& a, float4 w, float4 h) {
    a.x += w.x * h.x; a.y += w.y * h.y; a.z += w.z * h.z; a.w += w.w * h.w;
}
__device__ __forceinline__ float hsum4(float4 a) { return a.x + a.y + a.z + a.w; }

// ---------------------------------------------------------------------------
// K1: fused gather+MLP GEMM (unchanged — proven).
// ---------------------------------------------------------------------------
__global__ __launch_bounds__(256) void k_embed_gemm(const int* __restrict__ tok,
                                                    const float* __restrict__ W1,
                                                    const float* __restrict__ b1,
                                                    const float* __restrict__ W2,
                                                    const float* __restrict__ b2,
                                                    float* __restrict__ emb) {
    constexpr int BM = 64, BN = 64, BK = 32, K = 512, N = 256;
    __shared__ float As[BK][BM + 1];
    __shared__ float Bs[BK][BN];

    const int tid = threadIdx.x;
    const int bm = blockIdx.x * BM;
    const int bn = blockIdx.y * BN;
    const int tn = (tid & 15) * 4;
    const int tm = (tid >> 4) * 4;

    float acc[4][4] = {};

    for (int k0 = 0; k0 < K; k0 += BK) {
        for (int i = tid; i < BM * BK / 4; i += 256) {
            int c4 = (i & (BK / 4 - 1)) * 4;
            int r  = i / (BK / 4);
            int tv = tok[bm + r];
            float4 v  = *(const float4*)(W1 + (size_t)tv * K + k0 + c4);
            float4 bb = *(const float4*)(b1 + k0 + c4);
            As[c4 + 0][r] = thrf(v.x + bb.x);
            As[c4 + 1][r] = thrf(v.y + bb.y);
            As[c4 + 2][r] = thrf(v.z + bb.z);
            As[c4 + 3][r] = thrf(v.w + bb.w);
        }
        for (int i = tid; i < BK * BN / 4; i += 256) {
            int n4 = (i & 15) * 4;
            int kk = i >> 4;
            *(float4*)&Bs[kk][n4] = *(const float4*)(W2 + (size_t)(k0 + kk) * N + bn + n4);
        }
        __syncthreads();

        for (int k = 0; k < BK; ++k) {
            float a0 = As[k][tm + 0], a1 = As[k][tm + 1];
            float a2 = As[k][tm + 2], a3 = As[k][tm + 3];
            float b0 = Bs[k][tn + 0], b1v = Bs[k][tn + 1];
            float b2v = Bs[k][tn + 2], b3v = Bs[k][tn + 3];
            acc[0][0] += a0 * b0;  acc[0][1] += a0 * b1v;
            acc[0][2] += a0 * b2v; acc[0][3] += a0 * b3v;
            acc[1][0] += a1 * b0;  acc[1][1] += a1 * b1v;
            acc[1][2] += a1 * b2v; acc[1][3] += a1 * b3v;
            acc[2][0] += a2 * b0;  acc[2][1] += a2 * b1v;
            acc[2][2] += a2 * b2v; acc[2][3] += a2 * b3v;
            acc[3][0] += a3 * b0;  acc[3][1] += a3 * b1v;
            acc[3][2] += a3 * b2v; acc[3][3] += a3 * b3v;
        }
        __syncthreads();
    }

    const float4 bv = *(const float4*)(b2 + bn + tn);
    for (int i = 0; i < 4; ++i) {
        int m = bm + tm + i;
        float4 o;
        o.x = thrf(acc[i][0] + bv.x);
        o.y = thrf(acc[i][1] + bv.y);
        o.z = thrf(acc[i][2] + bv.z);
        o.w = thrf(acc[i][3] + bv.w);
        *(float4*)(emb + (size_t)m * N + bn + tn) = o;
    }
}

// ---------------------------------------------------------------------------
// K2: x_proj = emb @ W_ih^T + b_ih  (unchanged — proven).
// ---------------------------------------------------------------------------
__global__ __launch_bounds__(256) void k_xproj(const float* __restrict__ emb,   // (4096,256)
                                               const float* __restrict__ W_ih,  // (1536,256)
                                               const float* __restrict__ b_ih,  // (1536)
                                               float* __restrict__ xp) {        // (4096,1536)
    constexpr int BM = 128, BJ = 64, BK = 32, K = 256, J = 1536;
    __shared__ __align__(16) float As[BK][BM + 4];
    __shared__ __align__(16) float Bs[BK][BJ + 4];
    const int tid = threadIdx.x;
    const int bm = blockIdx.x * BM;
    const int bj = blockIdx.y * BJ;
    const int tj = (tid & 15) * 4;
    const int tm = (tid >> 4) * 8;

    float4 acc[8];
#pragma unroll
    for (int i = 0; i < 8; ++i) acc[i] = make_float4(0.f, 0.f, 0.f, 0.f);

    for (int k0 = 0; k0 < K; k0 += BK) {
#pragma unroll
        for (int p = 0; p < 4; ++p) {
            int i = tid + p * 256;
            int c4 = (i & 7) * 4, r = i >> 3;
            float4 v = *(const float4*)(emb + (size_t)(bm + r) * K + k0 + c4);
            As[c4 + 0][r] = v.x; As[c4 + 1][r] = v.y;
            As[c4 + 2][r] = v.z; As[c4 + 3][r] = v.w;
        }
#pragma unroll
        for (int p = 0; p < 2; ++p) {
            int i = tid + p * 256;
            int c4 = (i & 7) * 4, r = i >> 3;
            float4 v = *(const float4*)(W_ih + (size_t)(bj + r) * K + k0 + c4);
            Bs[c4 + 0][r] = v.x; Bs[c4 + 1][r] = v.y;
            Bs[c4 + 2][r] = v.z; Bs[c4 + 3][r] = v.w;
        }
        __syncthreads();

#pragma unroll 8
        for (int k = 0; k < BK; ++k) {
            float4 b4 = *(const float4*)&Bs[k][tj];
            float4 a0 = *(const float4*)&As[k][tm];
            float4 a1 = *(const float4*)&As[k][tm + 4];
            fma4(acc[0], a0.x, b4); fma4(acc[1], a0.y, b4);
            fma4(acc[2], a0.z, b4); fma4(acc[3], a0.w, b4);
            fma4(acc[4], a1.x, b4); fma4(acc[5], a1.y, b4);
            fma4(acc[6], a1.z, b4); fma4(acc[7], a1.w, b4);
        }
        __syncthreads();
    }

    const float4 bb = *(const float4*)(b_ih + bj + tj);
#pragma unroll
    for (int i = 0; i < 8; ++i) {
        float4 o = make_float4(acc[i].x + bb.x, acc[i].y + bb.y,
                               acc[i].z + bb.z, acc[i].w + bb.w);
        *(float4*)(xp + (size_t)(bm + tm + i) * J + bj + tj) = o;
    }
}

// ---------------------------------------------------------------------------
// Group barrier: 32 members, leaderless all-to-all flag scan.
// Proven primitive chain from the R0 kernel (syncthreads -> release fence +
// relaxed store -> relaxed poll -> acquire fence), generation-numbered,
// spin-limited (bug => wrong answer, never a hang).
// ---------------------------------------------------------------------------
__device__ __forceinline__ void gbar32(unsigned* __restrict__ flags,
                                       int g, int m, unsigned t1) {
    __syncthreads();   // all finalize stores issued (barrier drains vmcnt)
    if (threadIdx.x < 64) {
        if (threadIdx.x == 0) {
            __builtin_amdgcn_fence(__ATOMIC_RELEASE, "agent");
            __hip_atomic_store(&flags[(g * 32 + m) * 32], t1,
                               __ATOMIC_RELAXED, __HIP_MEMORY_SCOPE_AGENT);
        }
        if (threadIdx.x < 32) {
            int spins = 0;
            while (__hip_atomic_load(&flags[(g * 32 + threadIdx.x) * 32],
                                     __ATOMIC_RELAXED, __HIP_MEMORY_SCOPE_AGENT) < t1) {
                __builtin_amdgcn_s_sleep(1);
                if (++spins > SPIN_LIMIT) break;
            }
        }
        __builtin_amdgcn_fence(__ATOMIC_ACQUIRE, "agent");  // L1/L2 inv (CU-wide)
    }
    __syncthreads();
}

// ---------------------------------------------------------------------------
// K3 (rewritten): GRU scan with REGISTER-RESIDENT weights.
// 256 blocks x 256 threads = 8 groups (bid&7, XCD under round-robin) of 32
// members (bid>>3).  Member owns output slice jglob in [m*16, m*16+16);
// group owns batches [g*4, g*4+4).
//   - W_hh rows {j, 512+j, 1024+j} live in VGPRs (96 f32/thread) for all 128
//     steps -> per-step weight traffic ZERO (R2 was CU-load-bound re-reading
//     3MB/step: 54 B/cy/CU measured).
//   - thread (jl=tid&15, kc=tid>>4) covers k in {kc*4+c+64i}; h from LDS
//     (broadcast, conflict-free via stride 520); kc-reduce = 2 shfl_xor +
//     cross-wave LDS; 64 finalizers do gates, keep hprev in reg.
//   - per-step group exchange: 256B write + 8KB read of hbuf (ping-pong),
//     guarded by gbar32.
// ---------------------------------------------------------------------------
__global__ __launch_bounds__(256) void k_scan(const float* __restrict__ xp,    // (4096,1536)
                                              const float* __restrict__ W_hh,  // (1536,512)
                                              const float* __restrict__ b_hh,  // (1536)
                                              float* __restrict__ hbuf,        // (2,32,512)
                                              unsigned* __restrict__ flags,    // 8*32*32 u32, zeroed
                                              float* __restrict__ h_out) {     // (32,512)
    constexpr int HS = 520;                       // pad: conflict-free h reads
    __shared__ __align__(16) float hl[4][HS];     // group's 4 batch h vectors
    __shared__ float red[4][16][12];              // wave x j x (gate*4+b)

    const int tid = threadIdx.x;
    const int g   = blockIdx.x & 7;
    const int m   = blockIdx.x >> 3;
    const int jl  = tid & 15;
    const int kc  = tid >> 4;                     // 0..15
    const int jglob = m * 16 + jl;

    // ---- W rows -> registers (constant across all 128 steps) ----
    float4 wr[8], wz[8], wn[8];
#pragma unroll
    for (int i = 0; i < 8; ++i) {
        const int k = kc * 4 + i * 64;
        wr[i] = *(const float4*)(W_hh + (size_t)jglob * 512 + k);
        wz[i] = *(const float4*)(W_hh + (size_t)(512 + jglob) * 512 + k);
        wn[i] = *(const float4*)(W_hh + (size_t)(1024 + jglob) * 512 + k);
    }

    // finalizer persistent state (tid < 64): (jf, bf) -> one h element
    const int jf  = tid & 15;
    const int bf  = (tid >> 4) & 3;
    const int jfg = m * 16 + jf;
    const int bg  = g * 4 + bf;
    float bhr = 0.f, bhz = 0.f, bhn = 0.f, hprev = 0.f;
    if (tid < 64) {
        bhr = b_hh[jfg];
        bhz = b_hh[512 + jfg];
        bhn = b_hh[1024 + jfg];
    }

    // h(0) = 0
    for (int i = tid; i < 4 * HS; i += 256) ((float*)hl)[i] = 0.f;
    __syncthreads();

    for (int t = 0; t < 128; ++t) {
        // x(t) for finalizers — independent of h, hides under the dot phase
        float xr = 0.f, xz = 0.f, xn = 0.f;
        if (tid < 64) {
            const float* xrow = xp + (size_t)(t * 32 + bg) * 1536;
            xr = xrow[jfg];
            xz = xrow[512 + jfg];
            xn = xrow[1024 + jfg];
        }

        // ---- partial dots: 3 gates x 4 batches over this thread's k-set ----
        float p[3][4];
#pragma unroll
        for (int b = 0; b < 4; ++b) {
            float4 ar = make_float4(0.f, 0.f, 0.f, 0.f), az = ar, an = ar;
#pragma unroll
            for (int i = 0; i < 8; ++i) {
                float4 h4 = *(const float4*)&hl[b][kc * 4 + i * 64];
                macc4(ar, wr[i], h4);
                macc4(az, wz[i], h4);
                macc4(an, wn[i], h4);
            }
            p[0][b] = hsum4(ar); p[1][b] = hsum4(az); p[2][b] = hsum4(an);
        }

        // reduce over kc within wave (kc = lane bits 4,5)
#pragma unroll
        for (int gg = 0; gg < 3; ++gg)
#pragma unroll
            for (int b = 0; b < 4; ++b) {
                float v = p[gg][b];
                v += __shfl_xor(v, 16);
                v += __shfl_xor(v, 32);
                p[gg][b] = v;
            }
        if ((tid & 48) == 0) {          // lane<16 of each wave
            const int w = tid >> 6;
#pragma unroll
            for (int gg = 0; gg < 3; ++gg)
#pragma unroll
                for (int b = 0; b < 4; ++b)
                    red[w][jl][gg * 4 + b] = p[gg][b];
        }
        __syncthreads();

        // ---- finalize gates: 64 threads, one (j,b) each, hprev in reg ----
        if (tid < 64) {
            float sr = bhr, sz = bhz, sn = bhn;
#pragma unroll
            for (int w = 0; w < 4; ++w) {
                sr += red[w][jf][0 + bf];
                sz += red[w][jf][4 + bf];
                sn += red[w][jf][8 + bf];
            }
            float r  = sigm(xr + sr);
            float z  = sigm(xz + sz);
            float n  = tanhf(xn + r * sn);
            float hn = (1.0f - z) * n + z * hprev;
            hprev = hn;
            if (t < 127)
                hbuf[(size_t)((t + 1) & 1) * 16384 + (size_t)bg * 512 + jfg] = hn;
            else
                h_out[(size_t)bg * 512 + jfg] = hn;
        }

        if (t == 127) break;

        gbar32(flags, g, m, (unsigned)(t + 1));

        // reload group h(t+1) -> LDS (8KB, coalesced, stride-16B LDS writes)
        {
            const float* src = hbuf + (size_t)((t + 1) & 1) * 16384 + (size_t)(g * 4) * 512;
#pragma unroll
            for (int ph = 0; ph < 2; ++ph) {
                const int flat = tid * 4 + ph * 1024;
                const int b = flat >> 9, k = flat & 511;
                *(float4*)&hl[b][k] = *(const float4*)(src + (size_t)b * 512 + k);
            }
        }
        __syncthreads();
    }
}

// ---------------------------------------------------------------------------
// K4: head (unchanged).
// ---------------------------------------------------------------------------
__global__ __launch_bounds__(256) void k_head(const float* __restrict__ h,
                                              const float* __restrict__ W3,
                                              const float* __restrict__ b3,
                                              float* __restrict__ out) {
    const int b = blockIdx.x;
    const int o = threadIdx.x;
    const float* hrow = h + (size_t)b * 512;
    float acc = b3[o];
#pragma unroll 8
    for (int k = 0; k < 512; ++k)
        acc += hrow[k] * W3[(size_t)k * 256 + o];
    out[(size_t)b * 256 + o] = acc;
}

// ---------------------------------------------------------------------------
extern "C" void kernel_launch(void* const* d_in, const int* in_sizes, int n_in,
                              void* d_out, int out_size, void* d_ws, size_t ws_size,
                              hipStream_t stream) {
    // 0:input 1:W1 2:b1 3:W2 4:b2 5:W_ih 6:W_hh 7:b_ih 8:b_hh 9:W3 10:b3
    const int*   tok  = (const int*)d_in[0];
    const float* W1   = (const float*)d_in[1];
    const float* b1   = (const float*)d_in[2];
    const float* W2   = (const float*)d_in[3];
    const float* b2   = (const float*)d_in[4];
    const float* W_ih = (const float*)d_in[5];
    const float* W_hh = (const float*)d_in[6];
    const float* b_ih = (const float*)d_in[7];
    const float* b_hh = (const float*)d_in[8];
    const float* W3   = (const float*)d_in[9];
    const float* b3   = (const float*)d_in[10];
    float* out = (float*)d_out;
    (void)ws_size;

    // workspace (floats):
    //   emb  : 1,048,576   (4096x256)
    //   xp   : 6,291,456   (4096x1536)
    //   hbuf : 32,768      (2x32x512 ping-pong)
    //   hfin : 16,384      (32x512)
    //   flags: 8,192 u32   (8 groups x 32 members x 32-u32 spacing)
    float*    ws    = (float*)d_ws;
    float*    emb   = ws;
    float*    xp    = ws + 1048576;
    float*    hbuf  = ws + 7340032;
    float*    hfin  = ws + 7372800;
    unsigned* flags = (unsigned*)(ws + 7389184);

    (void)hipMemsetAsync(flags, 0, 8192 * sizeof(unsigned), stream);

    {   // fused embedding MLP
        dim3 grd(4096 / 64, 256 / 64);
        k_embed_gemm<<<grd, 256, 0, stream>>>(tok, W1, b1, W2, b2, emb);
    }
    {   // input projections for all timesteps (b_ih folded in)
        dim3 grd(4096 / 128, 1536 / 64);
        k_xproj<<<grd, 256, 0, stream>>>(emb, W_ih, b_ih, xp);
    }
    // register-resident-weight GRU scan: 8 groups x 32 members
    k_scan<<<256, 256, 0, stream>>>(xp, W_hh, b_hh, hbuf, flags, hfin);

    // head on final hidden state
    k_head<<<32, 256, 0, stream>>>(hfin, W3, b3, out);
}

// Round 4
// 708.692 us; speedup vs baseline: 15.3944x; 1.6357x over previous
//
#include <hip/hip_runtime.h>
#include <cstddef>

#define THRESH 1e-6f
#define SPIN_LIMIT (1 << 20)

__device__ __forceinline__ float thrf(float x) { return x > THRESH ? x : 0.0f; }
__device__ __forceinline__ float sigm(float x) { return 1.0f / (1.0f + expf(-x)); }
__device__ __forceinline__ void fma4(float4& c, float a, float4 b) {
    c.x += a * b.x; c.y += a * b.y; c.z += a * b.z; c.w += a * b.w;
}
__device__ __forceinline__ void macc4(float4& a, float4 w, float4 h) {
    a.x += w.x * h.x; a.y += w.y * h.y; a.z += w.z * h.z; a.w += w.w * h.w;
}
__device__ __forceinline__ float hsum4(float4 a) { return a.x + a.y + a.z + a.w; }

// ---------------------------------------------------------------------------
// K1: fused gather+MLP GEMM (unchanged — proven).
// ---------------------------------------------------------------------------
__global__ __launch_bounds__(256) void k_embed_gemm(const int* __restrict__ tok,
                                                    const float* __restrict__ W1,
                                                    const float* __restrict__ b1,
                                                    const float* __restrict__ W2,
                                                    const float* __restrict__ b2,
                                                    float* __restrict__ emb) {
    constexpr int BM = 64, BN = 64, BK = 32, K = 512, N = 256;
    __shared__ float As[BK][BM + 1];
    __shared__ float Bs[BK][BN];

    const int tid = threadIdx.x;
    const int bm = blockIdx.x * BM;
    const int bn = blockIdx.y * BN;
    const int tn = (tid & 15) * 4;
    const int tm = (tid >> 4) * 4;

    float acc[4][4] = {};

    for (int k0 = 0; k0 < K; k0 += BK) {
        for (int i = tid; i < BM * BK / 4; i += 256) {
            int c4 = (i & (BK / 4 - 1)) * 4;
            int r  = i / (BK / 4);
            int tv = tok[bm + r];
            float4 v  = *(const float4*)(W1 + (size_t)tv * K + k0 + c4);
            float4 bb = *(const float4*)(b1 + k0 + c4);
            As[c4 + 0][r] = thrf(v.x + bb.x);
            As[c4 + 1][r] = thrf(v.y + bb.y);
            As[c4 + 2][r] = thrf(v.z + bb.z);
            As[c4 + 3][r] = thrf(v.w + bb.w);
        }
        for (int i = tid; i < BK * BN / 4; i += 256) {
            int n4 = (i & 15) * 4;
            int kk = i >> 4;
            *(float4*)&Bs[kk][n4] = *(const float4*)(W2 + (size_t)(k0 + kk) * N + bn + n4);
        }
        __syncthreads();

        for (int k = 0; k < BK; ++k) {
            float a0 = As[k][tm + 0], a1 = As[k][tm + 1];
            float a2 = As[k][tm + 2], a3 = As[k][tm + 3];
            float b0 = Bs[k][tn + 0], b1v = Bs[k][tn + 1];
            float b2v = Bs[k][tn + 2], b3v = Bs[k][tn + 3];
            acc[0][0] += a0 * b0;  acc[0][1] += a0 * b1v;
            acc[0][2] += a0 * b2v; acc[0][3] += a0 * b3v;
            acc[1][0] += a1 * b0;  acc[1][1] += a1 * b1v;
            acc[1][2] += a1 * b2v; acc[1][3] += a1 * b3v;
            acc[2][0] += a2 * b0;  acc[2][1] += a2 * b1v;
            acc[2][2] += a2 * b2v; acc[2][3] += a2 * b3v;
            acc[3][0] += a3 * b0;  acc[3][1] += a3 * b1v;
            acc[3][2] += a3 * b2v; acc[3][3] += a3 * b3v;
        }
        __syncthreads();
    }

    const float4 bv = *(const float4*)(b2 + bn + tn);
    for (int i = 0; i < 4; ++i) {
        int m = bm + tm + i;
        float4 o;
        o.x = thrf(acc[i][0] + bv.x);
        o.y = thrf(acc[i][1] + bv.y);
        o.z = thrf(acc[i][2] + bv.z);
        o.w = thrf(acc[i][3] + bv.w);
        *(float4*)(emb + (size_t)m * N + bn + tn) = o;
    }
}

// ---------------------------------------------------------------------------
// K2: x_proj = emb @ W_ih^T + b_ih  (unchanged — proven).
// ---------------------------------------------------------------------------
__global__ __launch_bounds__(256) void k_xproj(const float* __restrict__ emb,   // (4096,256)
                                               const float* __restrict__ W_ih,  // (1536,256)
                                               const float* __restrict__ b_ih,  // (1536)
                                               float* __restrict__ xp) {        // (4096,1536)
    constexpr int BM = 128, BJ = 64, BK = 32, K = 256, J = 1536;
    __shared__ __align__(16) float As[BK][BM + 4];
    __shared__ __align__(16) float Bs[BK][BJ + 4];
    const int tid = threadIdx.x;
    const int bm = blockIdx.x * BM;
    const int bj = blockIdx.y * BJ;
    const int tj = (tid & 15) * 4;
    const int tm = (tid >> 4) * 8;

    float4 acc[8];
#pragma unroll
    for (int i = 0; i < 8; ++i) acc[i] = make_float4(0.f, 0.f, 0.f, 0.f);

    for (int k0 = 0; k0 < K; k0 += BK) {
#pragma unroll
        for (int p = 0; p < 4; ++p) {
            int i = tid + p * 256;
            int c4 = (i & 7) * 4, r = i >> 3;
            float4 v = *(const float4*)(emb + (size_t)(bm + r) * K + k0 + c4);
            As[c4 + 0][r] = v.x; As[c4 + 1][r] = v.y;
            As[c4 + 2][r] = v.z; As[c4 + 3][r] = v.w;
        }
#pragma unroll
        for (int p = 0; p < 2; ++p) {
            int i = tid + p * 256;
            int c4 = (i & 7) * 4, r = i >> 3;
            float4 v = *(const float4*)(W_ih + (size_t)(bj + r) * K + k0 + c4);
            Bs[c4 + 0][r] = v.x; Bs[c4 + 1][r] = v.y;
            Bs[c4 + 2][r] = v.z; Bs[c4 + 3][r] = v.w;
        }
        __syncthreads();

#pragma unroll 8
        for (int k = 0; k < BK; ++k) {
            float4 b4 = *(const float4*)&Bs[k][tj];
            float4 a0 = *(const float4*)&As[k][tm];
            float4 a1 = *(const float4*)&As[k][tm + 4];
            fma4(acc[0], a0.x, b4); fma4(acc[1], a0.y, b4);
            fma4(acc[2], a0.z, b4); fma4(acc[3], a0.w, b4);
            fma4(acc[4], a1.x, b4); fma4(acc[5], a1.y, b4);
            fma4(acc[6], a1.z, b4); fma4(acc[7], a1.w, b4);
        }
        __syncthreads();
    }

    const float4 bb = *(const float4*)(b_ih + bj + tj);
#pragma unroll
    for (int i = 0; i < 8; ++i) {
        float4 o = make_float4(acc[i].x + bb.x, acc[i].y + bb.y,
                               acc[i].z + bb.z, acc[i].w + bb.w);
        *(float4*)(xp + (size_t)(bm + tm + i) * J + bj + tj) = o;
    }
}

// ---------------------------------------------------------------------------
// K3: GRU scan, register-resident weights + LL (flag-in-data) exchange.
// 256 blocks x 256 threads = 8 groups (bid&7) x 32 members (bid>>3).
// Member owns j-slice [m*16, m*16+16); group owns batches [g*4, g*4+4).
//   - W_hh rows in VGPRs (96 f32/thread) for all 128 steps (R3, kept).
//   - h exchange: hx[parity][batch][j] holds u64 = (tag<<32)|float.
//     Producer: ONE relaxed agent atomic store per element (write-through
//     to coherence point; no fences, no wbl2/inv, no flags, no barrier).
//     Consumer: 8 u64 relaxed agent atomic loads per thread, poll until
//     tag == t (exact match: 0xAA poison can never match).  Data+flag in
//     one 8B word -> one coherence round trip per step (R3 took ~4, plus
//     a full L2 writeback+invalidate per block per step).
//   - Safety: the __syncthreads between LL-load and finalize-store means a
//     member only publishes tag t+1 after ALL its threads consumed tag t;
//     with parity ping-pong a slot is never overwritten before consumption.
//   - x(t) loads issued BEFORE the poll (latency hidden under it); xp now
//     stays L2-resident (no more per-step invalidates).
// ---------------------------------------------------------------------------
__global__ __launch_bounds__(256) void k_scan(const float* __restrict__ xp,    // (4096,1536)
                                              const float* __restrict__ W_hh,  // (1536,512)
                                              const float* __restrict__ b_hh,  // (1536)
                                              unsigned long long* __restrict__ hx, // (2,32,512) u64
                                              float* __restrict__ h_out) {     // (32,512)
    constexpr int HS = 520;                       // pad: conflict-free h reads
    __shared__ __align__(16) float hl[4][HS];     // group's 4 batch h vectors
    __shared__ float red[4][16][12];              // wave x j x (gate*4+b)

    const int tid = threadIdx.x;
    const int g   = blockIdx.x & 7;
    const int m   = blockIdx.x >> 3;
    const int jl  = tid & 15;
    const int kc  = tid >> 4;                     // 0..15
    const int jglob = m * 16 + jl;

    // ---- W rows -> registers (constant across all 128 steps) ----
    float4 wr[8], wz[8], wn[8];
#pragma unroll
    for (int i = 0; i < 8; ++i) {
        const int k = kc * 4 + i * 64;
        wr[i] = *(const float4*)(W_hh + (size_t)jglob * 512 + k);
        wz[i] = *(const float4*)(W_hh + (size_t)(512 + jglob) * 512 + k);
        wn[i] = *(const float4*)(W_hh + (size_t)(1024 + jglob) * 512 + k);
    }

    // finalizer persistent state (tid < 64): (jf, bf) -> one h element
    const int jf  = tid & 15;
    const int bf  = (tid >> 4) & 3;
    const int jfg = m * 16 + jf;
    const int bg  = g * 4 + bf;
    float bhr = 0.f, bhz = 0.f, bhn = 0.f, hprev = 0.f;
    if (tid < 64) {
        bhr = b_hh[jfg];
        bhz = b_hh[512 + jfg];
        bhn = b_hh[1024 + jfg];
    }

    // h(0) = 0
    for (int i = tid; i < 4 * HS; i += 256) ((float*)hl)[i] = 0.f;
    __syncthreads();

    for (int t = 0; t < 128; ++t) {
        // x(t) for finalizers — issued first so latency hides under the poll
        float xr = 0.f, xz = 0.f, xn = 0.f;
        if (tid < 64) {
            const float* xrow = xp + (size_t)(t * 32 + bg) * 1536;
            xr = xrow[jfg];
            xz = xrow[512 + jfg];
            xn = xrow[1024 + jfg];
        }

        // ---- LL receive of h(t) (t>0): poll tag-in-data, stage to LDS ----
        if (t > 0) {
            const unsigned tag = (unsigned)t;
            unsigned long long* base = hx + (size_t)(t & 1) * 16384 + (size_t)(g * 4) * 512;
            unsigned long long v[8];
#pragma unroll
            for (int p = 0; p < 8; ++p)
                v[p] = __hip_atomic_load(base + tid + 256 * p,
                                         __ATOMIC_RELAXED, __HIP_MEMORY_SCOPE_AGENT);
            int spins = 0;
            for (;;) {
                bool all = true;
#pragma unroll
                for (int p = 0; p < 8; ++p) {
                    if ((unsigned)(v[p] >> 32) != tag) {
                        all = false;
                        v[p] = __hip_atomic_load(base + tid + 256 * p,
                                                 __ATOMIC_RELAXED, __HIP_MEMORY_SCOPE_AGENT);
                    }
                }
                if (all || ++spins > SPIN_LIMIT) break;
                __builtin_amdgcn_s_sleep(1);
            }
#pragma unroll
            for (int p = 0; p < 8; ++p) {
                const int flat = tid + 256 * p;
                union { unsigned u; float f; } cv;
                cv.u = (unsigned)v[p];
                hl[flat >> 9][flat & 511] = cv.f;
            }
            __syncthreads();
        }

        // ---- partial dots: 3 gates x 4 batches over this thread's k-set ----
        float p[3][4];
#pragma unroll
        for (int b = 0; b < 4; ++b) {
            float4 ar = make_float4(0.f, 0.f, 0.f, 0.f), az = ar, an = ar;
#pragma unroll
            for (int i = 0; i < 8; ++i) {
                float4 h4 = *(const float4*)&hl[b][kc * 4 + i * 64];
                macc4(ar, wr[i], h4);
                macc4(az, wz[i], h4);
                macc4(an, wn[i], h4);
            }
            p[0][b] = hsum4(ar); p[1][b] = hsum4(az); p[2][b] = hsum4(an);
        }

        // reduce over kc within wave (kc = lane bits 4,5)
#pragma unroll
        for (int gg = 0; gg < 3; ++gg)
#pragma unroll
            for (int b = 0; b < 4; ++b) {
                float v = p[gg][b];
                v += __shfl_xor(v, 16);
                v += __shfl_xor(v, 32);
                p[gg][b] = v;
            }
        if ((tid & 48) == 0) {          // lane<16 of each wave
            const int w = tid >> 6;
#pragma unroll
            for (int gg = 0; gg < 3; ++gg)
#pragma unroll
                for (int b = 0; b < 4; ++b)
                    red[w][jl][gg * 4 + b] = p[gg][b];
        }
        __syncthreads();

        // ---- finalize gates: 64 threads, one (j,b) each; publish via LL ----
        if (tid < 64) {
            float sr = bhr, sz = bhz, sn = bhn;
#pragma unroll
            for (int w = 0; w < 4; ++w) {
                sr += red[w][jf][0 + bf];
                sz += red[w][jf][4 + bf];
                sn += red[w][jf][8 + bf];
            }
            float r  = sigm(xr + sr);
            float z  = sigm(xz + sz);
            float n  = tanhf(xn + r * sn);
            float hn = (1.0f - z) * n + z * hprev;
            hprev = hn;
            if (t < 127) {
                union { float f; unsigned u; } cv;
                cv.f = hn;
                const unsigned long long pk =
                    ((unsigned long long)(unsigned)(t + 1) << 32) | cv.u;
                __hip_atomic_store(hx + (size_t)((t + 1) & 1) * 16384 + (size_t)bg * 512 + jfg,
                                   pk, __ATOMIC_RELAXED, __HIP_MEMORY_SCOPE_AGENT);
            } else {
                h_out[(size_t)bg * 512 + jfg] = hn;
            }
        }
        // no bottom barrier: rushing threads only touch hl (next LL phase),
        // which nobody reads past the red-phase __syncthreads above.
    }
}

// ---------------------------------------------------------------------------
// K4: head (unchanged).
// ---------------------------------------------------------------------------
__global__ __launch_bounds__(256) void k_head(const float* __restrict__ h,
                                              const float* __restrict__ W3,
                                              const float* __restrict__ b3,
                                              float* __restrict__ out) {
    const int b = blockIdx.x;
    const int o = threadIdx.x;
    const float* hrow = h + (size_t)b * 512;
    float acc = b3[o];
#pragma unroll 8
    for (int k = 0; k < 512; ++k)
        acc += hrow[k] * W3[(size_t)k * 256 + o];
    out[(size_t)b * 256 + o] = acc;
}

// ---------------------------------------------------------------------------
extern "C" void kernel_launch(void* const* d_in, const int* in_sizes, int n_in,
                              void* d_out, int out_size, void* d_ws, size_t ws_size,
                              hipStream_t stream) {
    // 0:input 1:W1 2:b1 3:W2 4:b2 5:W_ih 6:W_hh 7:b_ih 8:b_hh 9:W3 10:b3
    const int*   tok  = (const int*)d_in[0];
    const float* W1   = (const float*)d_in[1];
    const float* b1   = (const float*)d_in[2];
    const float* W2   = (const float*)d_in[3];
    const float* b2   = (const float*)d_in[4];
    const float* W_ih = (const float*)d_in[5];
    const float* W_hh = (const float*)d_in[6];
    const float* b_ih = (const float*)d_in[7];
    const float* b_hh = (const float*)d_in[8];
    const float* W3   = (const float*)d_in[9];
    const float* b3   = (const float*)d_in[10];
    float* out = (float*)d_out;
    (void)ws_size;

    // workspace (floats):
    //   emb : 1,048,576      (4096x256)
    //   xp  : 6,291,456      (4096x1536)
    //   hx  : 65,536 f-equiv (2x32x512 u64 LL slots; exact-tag poll makes
    //                         0xAA poison — and any stale state — harmless)
    //   hfin: 16,384         (32x512)
    float* ws   = (float*)d_ws;
    float* emb  = ws;
    float* xp   = ws + 1048576;
    unsigned long long* hx = (unsigned long long*)(ws + 7340032);  // 8B-aligned
    float* hfin = ws + 7340032 + 65536;

    {   // fused embedding MLP
        dim3 grd(4096 / 64, 256 / 64);
        k_embed_gemm<<<grd, 256, 0, stream>>>(tok, W1, b1, W2, b2, emb);
    }
    {   // input projections for all timesteps (b_ih folded in)
        dim3 grd(4096 / 128, 1536 / 64);
        k_xproj<<<grd, 256, 0, stream>>>(emb, W_ih, b_ih, xp);
    }
    // register-resident-weight GRU scan with LL flag-in-data exchange
    k_scan<<<256, 256, 0, stream>>>(xp, W_hh, b_hh, hx, hfin);

    // head on final hidden state
    k_head<<<32, 256, 0, stream>>>(hfin, W3, b3, out);
}